// Round 12
// baseline (335.764 us; speedup 1.0000x reference)
//
#include <hip/hip_runtime.h>

#define D 64

// ---------------------------------------------------------------------------
// edge_index dtype detection (int32 vs int64), done per-block on device.
// int64 little-endian with values < 2^32 => every odd uint32 word is 0.
// int32 random indices in [0,100000): P(64 odd words all zero) ~ 1e-320.
// ---------------------------------------------------------------------------
#define DETECT_IS64(ei)                                        \
  __shared__ int s_is64;                                       \
  if (threadIdx.x == 0) {                                      \
    const unsigned int* w_ = (const unsigned int*)(ei);        \
    int is64_ = 1;                                             \
    for (int i_ = 0; i_ < 64; ++i_) {                          \
      if (w_[2 * i_ + 1] != 0u) { is64_ = 0; break; }          \
    }                                                          \
    s_is64 = is64_;                                            \
  }                                                            \
  __syncthreads();

// Grid/block for hist & place MUST be identical: shard = blockIdx & (S-1)
// must map each edge to the same shard in both kernels.
#define EDGE_GRID 4096
#define EDGE_BLOCK 256

// Scan parallelism: 8192 chunks (round-5 lesson: 1024 x 782 serial iters
// was 335 us at 0.18% occupancy; 8192 x ~98 restores latency hiding).
#define SCAN_CHUNKS 8192

// ---------------------------------------------------------------------------
// Kernel 1: sharded histogram. key = shard*N + dst, shard = blockIdx&(S-1).
// ---------------------------------------------------------------------------
__global__ __launch_bounds__(256) void gin_hist_sharded(
    const void* __restrict__ edge_index, int* __restrict__ C,
    int n_edges, int n_nodes, int nshard) {
  DETECT_IS64(edge_index);
  const int* ei32 = (const int*)edge_index;
  const long long* ei64 = (const long long*)edge_index;
  int* Cs = C + (size_t)(blockIdx.x & (nshard - 1)) * n_nodes;
  const int i = (int)(blockIdx.x * blockDim.x + threadIdx.x);
  const int stride = (int)(gridDim.x * blockDim.x);
  for (int e = i; e < n_edges; e += stride) {
    const int dst = s_is64 ? (int)ei64[n_edges + e] : ei32[n_edges + e];
    atomicAdd(&Cs[dst], 1);
  }
}

// ---------------------------------------------------------------------------
// Kernels 2a/2b/2c: in-place exclusive scan of C[total], SCAN_CHUNKS chunks.
// ---------------------------------------------------------------------------
__global__ __launch_bounds__(256) void gin_scan_a(
    const int* __restrict__ C, int* __restrict__ tsum, int total, int chunk) {
  const int t = (int)(blockIdx.x * blockDim.x + threadIdx.x);
  if (t >= SCAN_CHUNKS) return;
  const int beg = t * chunk;
  const int end = min(beg + chunk, total);
  int s = 0;
  for (int i = beg; i < end; ++i) s += C[i];
  tsum[t] = s;
}

// One block, 1024 threads; each thread owns 8 contiguous partials.
__global__ __launch_bounds__(1024) void gin_scan_b(int* __restrict__ tsum) {
  __shared__ int ls[1024];
  const int t = threadIdx.x;
  int v[8];
  int s = 0;
#pragma unroll
  for (int i = 0; i < 8; ++i) {
    v[i] = tsum[t * 8 + i];
    s += v[i];
  }
  ls[t] = s;
  __syncthreads();
  for (int o = 1; o < 1024; o <<= 1) {
    const int a = (t >= o) ? ls[t - o] : 0;
    __syncthreads();
    ls[t] += a;
    __syncthreads();
  }
  int run = ls[t] - s;  // exclusive over this thread's 8
#pragma unroll
  for (int i = 0; i < 8; ++i) {
    tsum[t * 8 + i] = run;
    run += v[i];
  }
}

__global__ __launch_bounds__(256) void gin_scan_c(
    int* __restrict__ C, const int* __restrict__ tsum, int total, int chunk) {
  const int t = (int)(blockIdx.x * blockDim.x + threadIdx.x);
  if (t >= SCAN_CHUNKS) return;
  const int beg = t * chunk;
  const int end = min(beg + chunk, total);
  int run = tsum[t];
  for (int i = beg; i < end; ++i) {
    const int c = C[i];
    C[i] = run;
    run += c;
  }
}

// ---------------------------------------------------------------------------
// Kernel 3: sharded placement. pos = atomicAdd(&C[shard*N+dst], 1).
// After this kernel, C[k] = exclusive_prefix[k+1].
// ---------------------------------------------------------------------------
__global__ __launch_bounds__(256) void gin_place_sharded(
    const void* __restrict__ edge_index, int* __restrict__ C,
    int* __restrict__ sorted_src, int n_edges, int n_nodes, int nshard) {
  DETECT_IS64(edge_index);
  const int* ei32 = (const int*)edge_index;
  const long long* ei64 = (const long long*)edge_index;
  int* Cs = C + (size_t)(blockIdx.x & (nshard - 1)) * n_nodes;
  const int i = (int)(blockIdx.x * blockDim.x + threadIdx.x);
  const int stride = (int)(gridDim.x * blockDim.x);
  for (int e = i; e < n_edges; e += stride) {
    int src, dst;
    if (s_is64) {
      src = (int)ei64[e];
      dst = (int)ei64[n_edges + e];
    } else {
      src = ei32[e];
      dst = ei32[n_edges + e];
    }
    const int pos = atomicAdd(&Cs[dst], 1);
    sorted_src[pos] = src;
  }
}

// ---------------------------------------------------------------------------
// Kernel 4: gather-aggregate, wave per node, PAIRED-EDGE branchless lockstep.
// Lane layout: h = lane>>5 (edge parity), f2 = lane&31 (feature pair).
// Each stream consumes 2 edges/iteration; a row is read as float2 by 32
// lanes. Round-11 lesson: single-edge lockstep was VALU-bound (77% busy,
// ~100 VALU wave-ops per 8 rows); pairing halves instructions per edge.
// Final cross-half combine: 2x shfl_xor(32) + predicated float2 store.
// ---------------------------------------------------------------------------
template <int S>
__global__ __launch_bounds__(256) void gin_gather_sharded(
    const float* __restrict__ x, const int* __restrict__ C,
    const int* __restrict__ sorted_src, float* __restrict__ agg,
    int n_nodes) {
  const int lane = (int)(threadIdx.x & 63);
  const int h = lane >> 5;    // which edge of the pair
  const int f2 = lane & 31;   // feature pair index
  const int wave = (int)((blockIdx.x * blockDim.x + threadIdx.x) >> 6);
  if (wave >= n_nodes) return;

  int p[S], q[S];
  float ax[S], ay[S];
  bool more = false;
#pragma unroll
  for (int s = 0; s < S; ++s) {
    const int k = s * n_nodes + wave;
    q[s] = C[k];
    p[s] = (k == 0) ? 0 : C[k - 1];
    ax[s] = 0.0f;
    ay[s] = 0.0f;
    more = more || (p[s] < q[s]);
  }

  while (more) {
    int act[S], srcs[S];
#pragma unroll
    for (int s = 0; s < S; ++s) {
      const int idx = p[s] + h;
      act[s] = (idx < q[s]) ? 1 : 0;
      srcs[s] = sorted_src[act[s] ? idx : 0];  // unconditional load
    }
    float2 rows[S];
#pragma unroll
    for (int s = 0; s < S; ++s) {
      rows[s] = *(const float2*)(x + (size_t)srcs[s] * D + f2 * 2);
    }
    more = false;
#pragma unroll
    for (int s = 0; s < S; ++s) {
      ax[s] += act[s] ? rows[s].x : 0.0f;
      ay[s] += act[s] ? rows[s].y : 0.0f;
      const int rem = q[s] - p[s];
      p[s] += (rem > 2) ? 2 : rem;  // consume up to 2
      more = more || (p[s] < q[s]);
    }
  }

  float rx = 0.0f, ry = 0.0f;
#pragma unroll
  for (int s = 0; s < S; ++s) {
    rx += ax[s];
    ry += ay[s];
  }
  // combine the two edge-parity halves (lane L <-> L^32)
  rx += __shfl_xor(rx, 32);
  ry += __shfl_xor(ry, 32);
  if (h == 0) {
    float2 r;
    r.x = rx;
    r.y = ry;
    *(float2*)(agg + (size_t)wave * D + f2 * 2) = r;
  }
}

// ---------------------------------------------------------------------------
// Fallback scatter (if ws too small): scalar float atomics, wave per edge.
// ---------------------------------------------------------------------------
__global__ __launch_bounds__(256) void gin_scatter_atomic(
    const float* __restrict__ x, const void* __restrict__ edge_index,
    float* __restrict__ agg, int n_edges) {
  DETECT_IS64(edge_index);
  const int* ei32 = (const int*)edge_index;
  const long long* ei64 = (const long long*)edge_index;
  const int lane = threadIdx.x & 63;
  int wave = (int)((blockIdx.x * blockDim.x + threadIdx.x) >> 6);
  const int nwaves = (int)((gridDim.x * blockDim.x) >> 6);
  for (int e = wave; e < n_edges; e += nwaves) {
    int src, dst;
    if (s_is64) {
      src = (int)ei64[e];
      dst = (int)ei64[n_edges + e];
    } else {
      src = ei32[e];
      dst = ei32[n_edges + e];
    }
    atomicAdd(&agg[(size_t)dst * D + lane], x[(size_t)src * D + lane]);
  }
}

// ---------------------------------------------------------------------------
// Kernel 5: block-tiled MLP (vector f32 GEMM). Unchanged from round 10
// (dropped out of top-5: predicted 25-35us).
// ---------------------------------------------------------------------------
__global__ __launch_bounds__(256) void gin_mlp_tiled(
    const float* __restrict__ x,
    const float* __restrict__ agg_in,
    const float* __restrict__ eps_p,
    const float* __restrict__ W1, const float* __restrict__ b1,
    const float* __restrict__ W2, const float* __restrict__ b2,
    float* __restrict__ out,
    int n_nodes) {
  __shared__ float zs[128 * 72];   // z tile; reused for h
  __shared__ float w1s[64 * 64];
  __shared__ float w2s[64 * 64];

  const int t = (int)threadIdx.x;
  const int base = (int)blockIdx.x * 128;
  const float scale = 1.0f + eps_p[0];

  // --- stage weights (kq-slot swizzled) ---
  {
    const float4* W1v = (const float4*)W1;
    const float4* W2v = (const float4*)W2;
#pragma unroll
    for (int i = 0; i < 4; ++i) {
      const int idx = t + 256 * i;  // 0..1023
      const int j = idx >> 4;
      const int kq = idx & 15;
      const int slot = kq ^ ((j >> 2) & 7);
      *(float4*)&w1s[j * 64 + slot * 4] = W1v[idx];
      *(float4*)&w2s[j * 64 + slot * 4] = W2v[idx];
    }
  }

  // --- stage z = scale*x + agg (zero-fill out-of-range rows) ---
  {
#pragma unroll
    for (int i = 0; i < 8; ++i) {
      const int idx = t + 256 * i;  // 0..2047
      const int row = idx >> 4;
      const int kq = idx & 15;
      const int g = base + row;
      float4 zv;
      zv.x = 0.0f; zv.y = 0.0f; zv.z = 0.0f; zv.w = 0.0f;
      if (g < n_nodes) {
        const float4 xv = *(const float4*)(x + (size_t)g * D + kq * 4);
        const float4 av = *(const float4*)(agg_in + (size_t)g * D + kq * 4);
        zv.x = scale * xv.x + av.x;
        zv.y = scale * xv.y + av.y;
        zv.z = scale * xv.z + av.z;
        zv.w = scale * xv.w + av.w;
      }
      *(float4*)&zs[row * 72 + kq * 4] = zv;
    }
  }
  __syncthreads();

  const int jg = t & 15;  // output quad: j = 4*jg + c
  const int mg = t >> 4;  // node sub-index: node = r*16 + mg
  const float4 b1q = ((const float4*)b1)[jg];
  const float4 b2q = ((const float4*)b2)[jg];
  const int wswz = (jg & 7);  // == ((j>>2)&7) for j = 4*jg+c, c<4

  float acc[8][4];
#pragma unroll
  for (int r = 0; r < 8; ++r) {
    acc[r][0] = b1q.x; acc[r][1] = b1q.y;
    acc[r][2] = b1q.z; acc[r][3] = b1q.w;
  }

  // --- layer 1: acc += z . W1^T ---
#pragma unroll 4
  for (int kq = 0; kq < 16; ++kq) {
    float4 wq[4];
#pragma unroll
    for (int c = 0; c < 4; ++c) {
      wq[c] = *(const float4*)&w1s[(4 * jg + c) * 64 + ((kq ^ wswz) * 4)];
    }
#pragma unroll
    for (int r = 0; r < 8; ++r) {
      const float4 zq = *(const float4*)&zs[(r * 16 + mg) * 72 + kq * 4];
#pragma unroll
      for (int c = 0; c < 4; ++c) {
        acc[r][c] += zq.x * wq[c].x + zq.y * wq[c].y +
                     zq.z * wq[c].z + zq.w * wq[c].w;
      }
    }
  }

  // --- relu, write h back into zs ---
  __syncthreads();  // all zs reads done
#pragma unroll
  for (int r = 0; r < 8; ++r) {
    float4 hv;
    hv.x = fmaxf(acc[r][0], 0.0f);
    hv.y = fmaxf(acc[r][1], 0.0f);
    hv.z = fmaxf(acc[r][2], 0.0f);
    hv.w = fmaxf(acc[r][3], 0.0f);
    *(float4*)&zs[(r * 16 + mg) * 72 + jg * 4] = hv;
  }
  __syncthreads();

  // --- layer 2: acc = b2 + h . W2^T ---
#pragma unroll
  for (int r = 0; r < 8; ++r) {
    acc[r][0] = b2q.x; acc[r][1] = b2q.y;
    acc[r][2] = b2q.z; acc[r][3] = b2q.w;
  }
#pragma unroll 4
  for (int kq = 0; kq < 16; ++kq) {
    float4 wq[4];
#pragma unroll
    for (int c = 0; c < 4; ++c) {
      wq[c] = *(const float4*)&w2s[(4 * jg + c) * 64 + ((kq ^ wswz) * 4)];
    }
#pragma unroll
    for (int r = 0; r < 8; ++r) {
      const float4 zq = *(const float4*)&zs[(r * 16 + mg) * 72 + kq * 4];
#pragma unroll
      for (int c = 0; c < 4; ++c) {
        acc[r][c] += zq.x * wq[c].x + zq.y * wq[c].y +
                     zq.z * wq[c].z + zq.w * wq[c].w;
      }
    }
  }

  // --- store out tile ---
#pragma unroll
  for (int r = 0; r < 8; ++r) {
    const int g = base + r * 16 + mg;
    if (g < n_nodes) {
      float4 ov;
      ov.x = acc[r][0]; ov.y = acc[r][1];
      ov.z = acc[r][2]; ov.w = acc[r][3];
      *(float4*)(out + (size_t)g * D + jg * 4) = ov;
    }
  }
}

extern "C" void kernel_launch(void* const* d_in, const int* in_sizes, int n_in,
                              void* d_out, int out_size, void* d_ws, size_t ws_size,
                              hipStream_t stream) {
  const float* x   = (const float*)d_in[0];
  const void*  ei  = d_in[1];
  const float* eps = (const float*)d_in[2];
  const float* W1  = (const float*)d_in[3];
  const float* b1  = (const float*)d_in[4];
  const float* W2  = (const float*)d_in[5];
  const float* b2  = (const float*)d_in[6];
  float* out = (float*)d_out;

  const int n_nodes = in_sizes[0] / D;
  const int n_edges = in_sizes[1] / 2;

  // Pick the largest shard count the workspace supports.
  // ws layout (ints): C[S*n_nodes] | tsum[SCAN_CHUNKS] | sorted[E]
  int S = 0;
  for (int cand = 8; cand >= 1; cand >>= 1) {
    const size_t need =
        ((size_t)cand * n_nodes + SCAN_CHUNKS + (size_t)n_edges) * 4;
    if (ws_size >= need) { S = cand; break; }
  }

  if (S > 0) {
    int* C      = (int*)d_ws;
    int* tsum   = C + (size_t)S * n_nodes;
    int* sorted = tsum + SCAN_CHUNKS;
    const int total = S * n_nodes;

    (void)hipMemsetAsync(C, 0, (size_t)total * 4, stream);

    gin_hist_sharded<<<EDGE_GRID, EDGE_BLOCK, 0, stream>>>(ei, C, n_edges,
                                                           n_nodes, S);

    const int chunk = (total + SCAN_CHUNKS - 1) / SCAN_CHUNKS;
    gin_scan_a<<<SCAN_CHUNKS / 256, 256, 0, stream>>>(C, tsum, total, chunk);
    gin_scan_b<<<1, 1024, 0, stream>>>(tsum);
    gin_scan_c<<<SCAN_CHUNKS / 256, 256, 0, stream>>>(C, tsum, total, chunk);

    gin_place_sharded<<<EDGE_GRID, EDGE_BLOCK, 0, stream>>>(ei, C, sorted,
                                                            n_edges, n_nodes,
                                                            S);

    const int gather_blocks = (n_nodes * 64 + 255) / 256;
    switch (S) {
      case 8:
        gin_gather_sharded<8><<<gather_blocks, 256, 0, stream>>>(
            x, C, sorted, out, n_nodes);
        break;
      case 4:
        gin_gather_sharded<4><<<gather_blocks, 256, 0, stream>>>(
            x, C, sorted, out, n_nodes);
        break;
      case 2:
        gin_gather_sharded<2><<<gather_blocks, 256, 0, stream>>>(
            x, C, sorted, out, n_nodes);
        break;
      default:
        gin_gather_sharded<1><<<gather_blocks, 256, 0, stream>>>(
            x, C, sorted, out, n_nodes);
        break;
    }
  } else {
    (void)hipMemsetAsync(out, 0, (size_t)n_nodes * D * sizeof(float), stream);
    gin_scatter_atomic<<<4096, 256, 0, stream>>>(x, ei, out, n_edges);
  }

  const int mlp_blocks = (n_nodes + 127) / 128;
  gin_mlp_tiled<<<mlp_blocks, 256, 0, stream>>>(x, out, eps, W1, b1, W2, b2,
                                                out, n_nodes);
}